// Round 3
// baseline (347.574 us; speedup 1.0000x reference)
//
#include <hip/hip_runtime.h>

#define TABLE_SIZE 4194304
#define NPTS (128*128*128)

// ---------------- Reduction: mean/std over ht[0:3, :] (3*TABLE_SIZE floats) ----

__global__ __launch_bounds__(256) void reduce_partial_kernel(
    const float4* __restrict__ ht4, double* __restrict__ part, int nblocks)
{
    const int total4 = 3 * TABLE_SIZE / 4;
    double s = 0.0, s2 = 0.0;
    int stride = gridDim.x * blockDim.x;
    for (int i = blockIdx.x * blockDim.x + threadIdx.x; i < total4; i += stride) {
        float4 v = ht4[i];
        double a = (double)v.x, b = (double)v.y, c = (double)v.z, d = (double)v.w;
        s  += a + b + c + d;
        s2 += a * a + b * b + c * c + d * d;
    }
    for (int off = 32; off > 0; off >>= 1) {
        s  += __shfl_down(s, off, 64);
        s2 += __shfl_down(s2, off, 64);
    }
    __shared__ double ls[4], ls2[4];
    int wid = threadIdx.x >> 6;
    if ((threadIdx.x & 63) == 0) { ls[wid] = s; ls2[wid] = s2; }
    __syncthreads();
    if (threadIdx.x == 0) {
        double a = 0.0, b = 0.0;
        for (int w = 0; w < 4; ++w) { a += ls[w]; b += ls2[w]; }
        part[blockIdx.x] = a;
        part[nblocks + blockIdx.x] = b;
    }
}

__global__ __launch_bounds__(256) void reduce_final_kernel(
    double* __restrict__ part, int nblocks)
{
    double s = 0.0, s2 = 0.0;
    for (int i = threadIdx.x; i < nblocks; i += blockDim.x) {
        s  += part[i];
        s2 += part[nblocks + i];
    }
    for (int off = 32; off > 0; off >>= 1) {
        s  += __shfl_down(s, off, 64);
        s2 += __shfl_down(s2, off, 64);
    }
    __shared__ double ls[4], ls2[4];
    int wid = threadIdx.x >> 6;
    if ((threadIdx.x & 63) == 0) { ls[wid] = s; ls2[wid] = s2; }
    __syncthreads();
    if (threadIdx.x == 0) {
        double a = 0.0, b = 0.0;
        for (int w = 0; w < 4; ++w) { a += ls[w]; b += ls2[w]; }
        double n = 3.0 * (double)TABLE_SIZE;
        double mean = a / n;
        double var = (b - n * mean * mean) / (n - 1.0);
        part[2 * nblocks]     = mean;
        part[2 * nblocks + 1] = 1.0 / sqrt(var);
    }
}

__device__ __forceinline__ float sigmoidf_acc(float x) {
    return 1.0f / (1.0f + expf(-x));
}

// ---------------- Pre-pass: transpose + activate + fold covariance ----------------
// 4 entries per thread. Entry j -> 16 floats at tab[4*j .. 4*j+3]:
//   [f0,f1,f2,c00] [c01,c02,c11,c12] [c22,sh0,sh1,sh2] [op,0,0,0]

__global__ __launch_bounds__(256) void transpose_activate_kernel(
    const float* __restrict__ ht,
    const float* __restrict__ farp,
    const int* __restrict__ vsp,
    const double* __restrict__ stats,
    float4* __restrict__ tab)
{
    int t = blockIdx.x * blockDim.x + threadIdx.x;   // entries 4t..4t+3; grid exact
    const float4* h4 = (const float4*)ht;

    float va[4][14];
    #pragma unroll
    for (int r = 0; r < 14; ++r) {
        float4 v = h4[(size_t)r * (TABLE_SIZE / 4) + t];
        va[0][r] = v.x; va[1][r] = v.y; va[2][r] = v.z; va[3][r] = v.w;
    }

    float far = farp[0];
    float vs  = (float)vsp[0];
    float scale_fac = 2.0f * far / vs;
    float mean   = (float)stats[0];
    float invstd = (float)stats[1];
    float nf = invstd * (scale_fac / 6.0f);

    #pragma unroll
    for (int e = 0; e < 4; ++e) {
        const float* p = va[e];
        float f0 = (p[0] - mean) * nf;
        float f1 = (p[1] - mean) * nf;
        float f2 = (p[2] - mean) * nf;
        float q0 = p[3], q1 = p[4], q2 = p[5], q3 = p[6];
        float s0 = sigmoidf_acc(p[7]) * scale_fac;
        float s1 = sigmoidf_acc(p[8]) * scale_fac;
        float s2 = sigmoidf_acc(p[9]) * scale_fac;
        float sh0 = sigmoidf_acc(p[10]);
        float sh1 = sigmoidf_acc(p[11]);
        float sh2 = sigmoidf_acc(p[12]);
        float op  = sigmoidf_acc(p[13] - 4.0f);

        float qn = 1.0f / sqrtf(q0 * q0 + q1 * q1 + q2 * q2 + q3 * q3);
        float r = q0 * qn, x = q1 * qn, y = q2 * qn, z = q3 * qn;

        float R00 = 1.0f - 2.0f * (y * y + z * z);
        float R01 = 2.0f * (x * y - r * z);
        float R02 = 2.0f * (x * z + r * y);
        float R10 = 2.0f * (x * y + r * z);
        float R11 = 1.0f - 2.0f * (x * x + z * z);
        float R12 = 2.0f * (y * z - r * x);
        float R20 = 2.0f * (x * z - r * y);
        float R21 = 2.0f * (y * z + r * x);
        float R22 = 1.0f - 2.0f * (x * x + y * y);

        float L00 = R00 * s0, L01 = R01 * s1, L02 = R02 * s2;
        float L10 = R10 * s0, L11 = R11 * s1, L12 = R12 * s2;
        float L20 = R20 * s0, L21 = R21 * s1, L22 = R22 * s2;

        float c00 = L00 * L00 + L01 * L01 + L02 * L02;
        float c01 = L00 * L10 + L01 * L11 + L02 * L12;
        float c02 = L00 * L20 + L01 * L21 + L02 * L22;
        float c11 = L10 * L10 + L11 * L11 + L12 * L12;
        float c12 = L10 * L20 + L11 * L21 + L12 * L22;
        float c22 = L20 * L20 + L21 * L21 + L22 * L22;

        int j = 4 * t + e;
        tab[4 * j + 0] = make_float4(f0, f1, f2, c00);
        tab[4 * j + 1] = make_float4(c01, c02, c11, c12);
        tab[4 * j + 2] = make_float4(c22, sh0, sh1, sh2);
        tab[4 * j + 3] = make_float4(op, 0.0f, 0.0f, 0.0f);
    }
}

// ---------------- Main per-point kernel (gather path), 4 points/thread ----------------

__global__ __launch_bounds__(256) void HashTableVoxelizedGaussianAdapterModule_86990267613197_kernel(
    const int4* __restrict__ cvec,
    const float4* __restrict__ tab,
    const float* __restrict__ cam,
    const float* __restrict__ farp,
    const int* __restrict__ vsp,
    float4* __restrict__ out)
{
    int t = blockIdx.x * blockDim.x + threadIdx.x;   // points 4t..4t+3; grid exact

    int4 A = cvec[3 * t + 0];
    int4 B = cvec[3 * t + 1];
    int4 C = cvec[3 * t + 2];

    int cx[4] = {A.x, A.w, B.z, C.y};
    int cy[4] = {A.y, B.x, B.w, C.z};
    int cz[4] = {A.z, B.y, C.x, C.w};

    float4 e0[4], e1[4], e2[4], e3[4];
    #pragma unroll
    for (int p = 0; p < 4; ++p) {
        unsigned int h = (unsigned int)cx[p] * 1u
                       ^ (unsigned int)cy[p] * 2654435761u
                       ^ (unsigned int)cz[p] * 805459861u;
        int idx = (int)(h & (unsigned int)(TABLE_SIZE - 1));
        e0[p] = tab[4 * idx + 0];
        e1[p] = tab[4 * idx + 1];
        e2[p] = tab[4 * idx + 2];
        e3[p] = tab[4 * idx + 3];
    }

    float far = farp[0];
    float vs  = (float)vsp[0];
    float k   = 2.0f * far / vs;
    float off = -far + far / vs;
    float camx = cam[0], camy = cam[1], camz = cam[2];

    #pragma unroll
    for (int p = 0; p < 4; ++p) {
        float vcx = (float)cx[p] * k + off + camx;
        float vcy = (float)cy[p] * k + off + camy;
        float vcz = (float)cz[p] * k + off + camz;
        int i = 4 * t + p;
        out[4 * i + 0] = make_float4(e0[p].x + vcx, e0[p].y + vcy, e0[p].z + vcz, e0[p].w);
        out[4 * i + 1] = make_float4(e1[p].x, e1[p].y, e1[p].x, e1[p].z);   // c01 c02 c01 c11
        out[4 * i + 2] = make_float4(e1[p].w, e1[p].y, e1[p].w, e2[p].x);   // c12 c02 c12 c22
        out[4 * i + 3] = make_float4(e2[p].y, e2[p].z, e2[p].w, e3[p].x);   // sh0 sh1 sh2 op
    }
}

// ---------------- Fallback direct kernel (if ws too small) ----------------

__global__ __launch_bounds__(256) void direct_kernel(
    const int* __restrict__ coords,
    const float* __restrict__ ht,
    const float* __restrict__ cam,
    const float* __restrict__ farp,
    const int* __restrict__ vsp,
    const double* __restrict__ stats,
    float* __restrict__ out)
{
    int i = blockIdx.x * blockDim.x + threadIdx.x;
    if (i >= NPTS) return;

    int c0 = coords[3 * i + 0];
    int c1 = coords[3 * i + 1];
    int c2 = coords[3 * i + 2];

    unsigned int h = (unsigned int)c0 * 1u
                   ^ (unsigned int)c1 * 2654435761u
                   ^ (unsigned int)c2 * 805459861u;
    int idx = (int)(h & (unsigned int)(TABLE_SIZE - 1));

    float far = farp[0];
    float vs  = (float)vsp[0];
    float scale_fac = 2.0f * far / vs;
    float mean   = (float)stats[0];
    float invstd = (float)stats[1];

    const float* p = ht + idx;
    float nf = invstd * (scale_fac / 6.0f);
    float f0 = (p[0 * TABLE_SIZE] - mean) * nf;
    float f1 = (p[1 * TABLE_SIZE] - mean) * nf;
    float f2 = (p[2 * TABLE_SIZE] - mean) * nf;
    float q0 = p[3 * TABLE_SIZE];
    float q1 = p[4 * TABLE_SIZE];
    float q2 = p[5 * TABLE_SIZE];
    float q3 = p[6 * TABLE_SIZE];
    float s0 = sigmoidf_acc(p[7 * TABLE_SIZE]) * scale_fac;
    float s1 = sigmoidf_acc(p[8 * TABLE_SIZE]) * scale_fac;
    float s2 = sigmoidf_acc(p[9 * TABLE_SIZE]) * scale_fac;
    float sh0 = sigmoidf_acc(p[10 * TABLE_SIZE]);
    float sh1 = sigmoidf_acc(p[11 * TABLE_SIZE]);
    float sh2 = sigmoidf_acc(p[12 * TABLE_SIZE]);
    float op  = sigmoidf_acc(p[13 * TABLE_SIZE] - 4.0f);

    float k = 2.0f * far / vs;
    float off = -far + far / vs;
    float vcx = (float)c0 * k + off + cam[0];
    float vcy = (float)c1 * k + off + cam[1];
    float vcz = (float)c2 * k + off + cam[2];

    float qn = 1.0f / sqrtf(q0 * q0 + q1 * q1 + q2 * q2 + q3 * q3);
    float r = q0 * qn, x = q1 * qn, y = q2 * qn, z = q3 * qn;

    float R00 = 1.0f - 2.0f * (y * y + z * z);
    float R01 = 2.0f * (x * y - r * z);
    float R02 = 2.0f * (x * z + r * y);
    float R10 = 2.0f * (x * y + r * z);
    float R11 = 1.0f - 2.0f * (x * x + z * z);
    float R12 = 2.0f * (y * z - r * x);
    float R20 = 2.0f * (x * z - r * y);
    float R21 = 2.0f * (y * z + r * x);
    float R22 = 1.0f - 2.0f * (x * x + y * y);

    float L00 = R00 * s0, L01 = R01 * s1, L02 = R02 * s2;
    float L10 = R10 * s0, L11 = R11 * s1, L12 = R12 * s2;
    float L20 = R20 * s0, L21 = R21 * s1, L22 = R22 * s2;

    float c00 = L00 * L00 + L01 * L01 + L02 * L02;
    float c01 = L00 * L10 + L01 * L11 + L02 * L12;
    float c02 = L00 * L20 + L01 * L21 + L02 * L22;
    float c11 = L10 * L10 + L11 * L11 + L12 * L12;
    float c12 = L10 * L20 + L11 * L21 + L12 * L22;
    float c22 = L20 * L20 + L21 * L21 + L22 * L22;

    float4* o = (float4*)(out + 16LL * i);
    o[0] = make_float4(f0 + vcx, f1 + vcy, f2 + vcz, c00);
    o[1] = make_float4(c01, c02, c01, c11);
    o[2] = make_float4(c12, c02, c12, c22);
    o[3] = make_float4(sh0, sh1, sh2, op);
}

// ---------------- Launch ----------------

extern "C" void kernel_launch(void* const* d_in, const int* in_sizes, int n_in,
                              void* d_out, int out_size, void* d_ws, size_t ws_size,
                              hipStream_t stream) {
    const int*   coords = (const int*)d_in[0];
    const float* ht     = (const float*)d_in[1];
    const float* cam    = (const float*)d_in[2];
    const float* farp   = (const float*)d_in[3];
    const int*   vsp    = (const int*)d_in[4];
    float* out = (float*)d_out;

    const int nb = 1024;                       // reduction blocks
    const size_t red_bytes = 32768;            // reserve (needs 2*nb+2 doubles = 16.4 KB)
    const size_t tab_bytes = (size_t)TABLE_SIZE * 16 * sizeof(float);   // 268.4 MB

    double* ws = (double*)d_ws;

    reduce_partial_kernel<<<nb, 256, 0, stream>>>((const float4*)ht, ws, nb);
    reduce_final_kernel<<<1, 256, 0, stream>>>(ws, nb);
    const double* stats = ws + 2 * nb;

    if (ws_size >= red_bytes + tab_bytes) {
        float4* tab = (float4*)((char*)d_ws + red_bytes);
        transpose_activate_kernel<<<TABLE_SIZE / 4 / 256, 256, 0, stream>>>(
            ht, farp, vsp, stats, tab);
        HashTableVoxelizedGaussianAdapterModule_86990267613197_kernel<<<NPTS / 4 / 256, 256, 0, stream>>>(
            (const int4*)coords, tab, cam, farp, vsp, (float4*)out);
    } else {
        direct_kernel<<<(NPTS + 255) / 256, 256, 0, stream>>>(
            coords, ht, cam, farp, vsp, stats, out);
    }
}

// Round 4
// 259.620 us; speedup vs baseline: 1.3388x; 1.3388x over previous
//
#include <hip/hip_runtime.h>

#define TABLE_SIZE 4194304
#define NPTS (128*128*128)
#define HALF (TABLE_SIZE / 2)

__device__ __forceinline__ float sigmoidf_acc(float x) {
    return 1.0f / (1.0f + expf(-x));
}

// ---------------- Fused pre-pass: activate + fold covariance + partial mean/var ----
// 2 entries per thread (t and t+HALF). Entry j -> 16 floats at tab[4*j .. 4*j+3]:
//   [p0,p1,p2,c00] [c01,c02,c11,c12] [c22,sh0,sh1,sh2] [op,0,0,0]
// (p0..p2 RAW; normalization folded into gather kernel.)
// Side output: per-block sum / sumsq over rows 0..2.

__device__ __forceinline__ void make_entry(
    const float* p, float scale_fac, float4* tab, int j)
{
    float q0 = p[3], q1 = p[4], q2 = p[5], q3 = p[6];
    float s0 = sigmoidf_acc(p[7]) * scale_fac;
    float s1 = sigmoidf_acc(p[8]) * scale_fac;
    float s2 = sigmoidf_acc(p[9]) * scale_fac;
    float sh0 = sigmoidf_acc(p[10]);
    float sh1 = sigmoidf_acc(p[11]);
    float sh2 = sigmoidf_acc(p[12]);
    float op  = sigmoidf_acc(p[13] - 4.0f);

    float qn = 1.0f / sqrtf(q0 * q0 + q1 * q1 + q2 * q2 + q3 * q3);
    float r = q0 * qn, x = q1 * qn, y = q2 * qn, z = q3 * qn;

    float R00 = 1.0f - 2.0f * (y * y + z * z);
    float R01 = 2.0f * (x * y - r * z);
    float R02 = 2.0f * (x * z + r * y);
    float R10 = 2.0f * (x * y + r * z);
    float R11 = 1.0f - 2.0f * (x * x + z * z);
    float R12 = 2.0f * (y * z - r * x);
    float R20 = 2.0f * (x * z - r * y);
    float R21 = 2.0f * (y * z + r * x);
    float R22 = 1.0f - 2.0f * (x * x + y * y);

    float L00 = R00 * s0, L01 = R01 * s1, L02 = R02 * s2;
    float L10 = R10 * s0, L11 = R11 * s1, L12 = R12 * s2;
    float L20 = R20 * s0, L21 = R21 * s1, L22 = R22 * s2;

    float c00 = L00 * L00 + L01 * L01 + L02 * L02;
    float c01 = L00 * L10 + L01 * L11 + L02 * L12;
    float c02 = L00 * L20 + L01 * L21 + L02 * L22;
    float c11 = L10 * L10 + L11 * L11 + L12 * L12;
    float c12 = L10 * L20 + L11 * L21 + L12 * L22;
    float c22 = L20 * L20 + L21 * L21 + L22 * L22;

    tab[4 * j + 0] = make_float4(p[0], p[1], p[2], c00);
    tab[4 * j + 1] = make_float4(c01, c02, c11, c12);
    tab[4 * j + 2] = make_float4(c22, sh0, sh1, sh2);
    tab[4 * j + 3] = make_float4(op, 0.0f, 0.0f, 0.0f);
}

__global__ __launch_bounds__(256) void prepass_kernel(
    const float* __restrict__ ht,
    const float* __restrict__ farp,
    const int* __restrict__ vsp,
    double* __restrict__ part, int nblocks,
    float4* __restrict__ tab)
{
    int t = blockIdx.x * blockDim.x + threadIdx.x;   // entries t and t+HALF; grid exact

    float a[14], b[14];
    #pragma unroll
    for (int r = 0; r < 14; ++r) a[r] = ht[(size_t)r * TABLE_SIZE + t];
    #pragma unroll
    for (int r = 0; r < 14; ++r) b[r] = ht[(size_t)r * TABLE_SIZE + t + HALF];

    float far = farp[0];
    float vs  = (float)vsp[0];
    float scale_fac = 2.0f * far / vs;

    make_entry(a, scale_fac, tab, t);
    make_entry(b, scale_fac, tab, t + HALF);

    // partial sum / sumsq over rows 0..2 (both entries)
    double s  = (double)a[0] + (double)a[1] + (double)a[2]
              + (double)b[0] + (double)b[1] + (double)b[2];
    double s2 = (double)a[0]*a[0] + (double)a[1]*a[1] + (double)a[2]*a[2]
              + (double)b[0]*b[0] + (double)b[1]*b[1] + (double)b[2]*b[2];

    for (int off = 32; off > 0; off >>= 1) {
        s  += __shfl_down(s, off, 64);
        s2 += __shfl_down(s2, off, 64);
    }
    __shared__ double ls[4], ls2[4];
    int wid = threadIdx.x >> 6;
    if ((threadIdx.x & 63) == 0) { ls[wid] = s; ls2[wid] = s2; }
    __syncthreads();
    if (threadIdx.x == 0) {
        double sa = 0.0, sb = 0.0;
        for (int w = 0; w < 4; ++w) { sa += ls[w]; sb += ls2[w]; }
        part[blockIdx.x] = sa;
        part[nblocks + blockIdx.x] = sb;
    }
}

__global__ __launch_bounds__(256) void reduce_final_kernel(
    double* __restrict__ part, int nblocks)
{
    double s = 0.0, s2 = 0.0;
    for (int i = threadIdx.x; i < nblocks; i += blockDim.x) {
        s  += part[i];
        s2 += part[nblocks + i];
    }
    for (int off = 32; off > 0; off >>= 1) {
        s  += __shfl_down(s, off, 64);
        s2 += __shfl_down(s2, off, 64);
    }
    __shared__ double ls[4], ls2[4];
    int wid = threadIdx.x >> 6;
    if ((threadIdx.x & 63) == 0) { ls[wid] = s; ls2[wid] = s2; }
    __syncthreads();
    if (threadIdx.x == 0) {
        double a = 0.0, b = 0.0;
        for (int w = 0; w < 4; ++w) { a += ls[w]; b += ls2[w]; }
        double n = 3.0 * (double)TABLE_SIZE;
        double mean = a / n;
        double var = (b - n * mean * mean) / (n - 1.0);
        part[2 * nblocks]     = mean;
        part[2 * nblocks + 1] = 1.0 / sqrt(var);
    }
}

// ---------------- Main per-point kernel (gather path, round-2 pattern) ------------

__global__ __launch_bounds__(256) void HashTableVoxelizedGaussianAdapterModule_86990267613197_kernel(
    const int* __restrict__ coords,
    const float4* __restrict__ tab,
    const float* __restrict__ cam,
    const float* __restrict__ farp,
    const int* __restrict__ vsp,
    const double* __restrict__ stats,
    float4* __restrict__ out)
{
    int i = blockIdx.x * blockDim.x + threadIdx.x;   // exact grid: NPTS/256

    int c0 = coords[3 * i + 0];
    int c1 = coords[3 * i + 1];
    int c2 = coords[3 * i + 2];

    unsigned int h = (unsigned int)c0 * 1u
                   ^ (unsigned int)c1 * 2654435761u
                   ^ (unsigned int)c2 * 805459861u;
    int idx = (int)(h & (unsigned int)(TABLE_SIZE - 1));

    float4 e0 = tab[4 * idx + 0];
    float4 e1 = tab[4 * idx + 1];
    float4 e2 = tab[4 * idx + 2];
    float4 e3 = tab[4 * idx + 3];

    float far = farp[0];
    float vs  = (float)vsp[0];
    float k   = 2.0f * far / vs;
    float off = -far + far / vs;

    float mean   = (float)stats[0];
    float invstd = (float)stats[1];
    float nf = invstd * (k / 6.0f);          // k == scale_fac

    float vcx = (float)c0 * k + off + cam[0];
    float vcy = (float)c1 * k + off + cam[1];
    float vcz = (float)c2 * k + off + cam[2];

    out[4 * i + 0] = make_float4((e0.x - mean) * nf + vcx,
                                 (e0.y - mean) * nf + vcy,
                                 (e0.z - mean) * nf + vcz, e0.w);
    out[4 * i + 1] = make_float4(e1.x, e1.y, e1.x, e1.z);   // c01 c02 c01 c11
    out[4 * i + 2] = make_float4(e1.w, e1.y, e1.w, e2.x);   // c12 c02 c12 c22
    out[4 * i + 3] = make_float4(e2.y, e2.z, e2.w, e3.x);   // sh0 sh1 sh2 op
}

// ---------------- Fallback path (ws too small): reduction + direct kernel ---------

__global__ __launch_bounds__(256) void reduce_partial_kernel(
    const float4* __restrict__ ht4, double* __restrict__ part, int nblocks)
{
    const int total4 = 3 * TABLE_SIZE / 4;
    double s = 0.0, s2 = 0.0;
    int stride = gridDim.x * blockDim.x;
    for (int i = blockIdx.x * blockDim.x + threadIdx.x; i < total4; i += stride) {
        float4 v = ht4[i];
        double a = (double)v.x, b = (double)v.y, c = (double)v.z, d = (double)v.w;
        s  += a + b + c + d;
        s2 += a * a + b * b + c * c + d * d;
    }
    for (int off = 32; off > 0; off >>= 1) {
        s  += __shfl_down(s, off, 64);
        s2 += __shfl_down(s2, off, 64);
    }
    __shared__ double ls[4], ls2[4];
    int wid = threadIdx.x >> 6;
    if ((threadIdx.x & 63) == 0) { ls[wid] = s; ls2[wid] = s2; }
    __syncthreads();
    if (threadIdx.x == 0) {
        double a = 0.0, b = 0.0;
        for (int w = 0; w < 4; ++w) { a += ls[w]; b += ls2[w]; }
        part[blockIdx.x] = a;
        part[nblocks + blockIdx.x] = b;
    }
}

__global__ __launch_bounds__(256) void direct_kernel(
    const int* __restrict__ coords,
    const float* __restrict__ ht,
    const float* __restrict__ cam,
    const float* __restrict__ farp,
    const int* __restrict__ vsp,
    const double* __restrict__ stats,
    float* __restrict__ out)
{
    int i = blockIdx.x * blockDim.x + threadIdx.x;
    if (i >= NPTS) return;

    int c0 = coords[3 * i + 0];
    int c1 = coords[3 * i + 1];
    int c2 = coords[3 * i + 2];

    unsigned int h = (unsigned int)c0 * 1u
                   ^ (unsigned int)c1 * 2654435761u
                   ^ (unsigned int)c2 * 805459861u;
    int idx = (int)(h & (unsigned int)(TABLE_SIZE - 1));

    float far = farp[0];
    float vs  = (float)vsp[0];
    float scale_fac = 2.0f * far / vs;
    float mean   = (float)stats[0];
    float invstd = (float)stats[1];

    const float* p = ht + idx;
    float nf = invstd * (scale_fac / 6.0f);
    float f0 = (p[0 * TABLE_SIZE] - mean) * nf;
    float f1 = (p[1 * TABLE_SIZE] - mean) * nf;
    float f2 = (p[2 * TABLE_SIZE] - mean) * nf;
    float q0 = p[3 * TABLE_SIZE];
    float q1 = p[4 * TABLE_SIZE];
    float q2 = p[5 * TABLE_SIZE];
    float q3 = p[6 * TABLE_SIZE];
    float s0 = sigmoidf_acc(p[7 * TABLE_SIZE]) * scale_fac;
    float s1 = sigmoidf_acc(p[8 * TABLE_SIZE]) * scale_fac;
    float s2 = sigmoidf_acc(p[9 * TABLE_SIZE]) * scale_fac;
    float sh0 = sigmoidf_acc(p[10 * TABLE_SIZE]);
    float sh1 = sigmoidf_acc(p[11 * TABLE_SIZE]);
    float sh2 = sigmoidf_acc(p[12 * TABLE_SIZE]);
    float op  = sigmoidf_acc(p[13 * TABLE_SIZE] - 4.0f);

    float k = 2.0f * far / vs;
    float off = -far + far / vs;
    float vcx = (float)c0 * k + off + cam[0];
    float vcy = (float)c1 * k + off + cam[1];
    float vcz = (float)c2 * k + off + cam[2];

    float qn = 1.0f / sqrtf(q0 * q0 + q1 * q1 + q2 * q2 + q3 * q3);
    float r = q0 * qn, x = q1 * qn, y = q2 * qn, z = q3 * qn;

    float R00 = 1.0f - 2.0f * (y * y + z * z);
    float R01 = 2.0f * (x * y - r * z);
    float R02 = 2.0f * (x * z + r * y);
    float R10 = 2.0f * (x * y + r * z);
    float R11 = 1.0f - 2.0f * (x * x + z * z);
    float R12 = 2.0f * (y * z - r * x);
    float R20 = 2.0f * (x * z - r * y);
    float R21 = 2.0f * (y * z + r * x);
    float R22 = 1.0f - 2.0f * (x * x + y * y);

    float L00 = R00 * s0, L01 = R01 * s1, L02 = R02 * s2;
    float L10 = R10 * s0, L11 = R11 * s1, L12 = R12 * s2;
    float L20 = R20 * s0, L21 = R21 * s1, L22 = R22 * s2;

    float c00 = L00 * L00 + L01 * L01 + L02 * L02;
    float c01 = L00 * L10 + L01 * L11 + L02 * L12;
    float c02 = L00 * L20 + L01 * L21 + L02 * L22;
    float c11 = L10 * L10 + L11 * L11 + L12 * L12;
    float c12 = L10 * L20 + L11 * L21 + L12 * L22;
    float c22 = L20 * L20 + L21 * L21 + L22 * L22;

    float4* o = (float4*)(out + 16LL * i);
    o[0] = make_float4(f0 + vcx, f1 + vcy, f2 + vcz, c00);
    o[1] = make_float4(c01, c02, c01, c11);
    o[2] = make_float4(c12, c02, c12, c22);
    o[3] = make_float4(sh0, sh1, sh2, op);
}

// ---------------- Launch ----------------

extern "C" void kernel_launch(void* const* d_in, const int* in_sizes, int n_in,
                              void* d_out, int out_size, void* d_ws, size_t ws_size,
                              hipStream_t stream) {
    const int*   coords = (const int*)d_in[0];
    const float* ht     = (const float*)d_in[1];
    const float* cam    = (const float*)d_in[2];
    const float* farp   = (const float*)d_in[3];
    const int*   vsp    = (const int*)d_in[4];
    float* out = (float*)d_out;

    const int nbA = HALF / 256;                               // 8192 pre-pass blocks
    const size_t red_bytes = (((2 * (size_t)nbA + 2) * sizeof(double)) + 4095) & ~(size_t)4095;
    const size_t tab_bytes = (size_t)TABLE_SIZE * 16 * sizeof(float);   // 268.4 MB

    double* ws = (double*)d_ws;

    if (ws_size >= red_bytes + tab_bytes) {
        float4* tab = (float4*)((char*)d_ws + red_bytes);
        prepass_kernel<<<nbA, 256, 0, stream>>>(ht, farp, vsp, ws, nbA, tab);
        reduce_final_kernel<<<1, 256, 0, stream>>>(ws, nbA);
        const double* stats = ws + 2 * nbA;
        HashTableVoxelizedGaussianAdapterModule_86990267613197_kernel<<<NPTS / 256, 256, 0, stream>>>(
            coords, tab, cam, farp, vsp, stats, (float4*)out);
    } else {
        const int nb = 1024;
        reduce_partial_kernel<<<nb, 256, 0, stream>>>((const float4*)ht, ws, nb);
        reduce_final_kernel<<<1, 256, 0, stream>>>(ws, nb);
        const double* stats = ws + 2 * nb;
        direct_kernel<<<(NPTS + 255) / 256, 256, 0, stream>>>(
            coords, ht, cam, farp, vsp, stats, out);
    }
}

// Round 6
// 187.795 us; speedup vs baseline: 1.8508x; 1.3825x over previous
//
#include <hip/hip_runtime.h>
#include <hip/hip_fp16.h>

#define TABLE_SIZE 4194304
#define NPTS (128*128*128)

typedef float f4v __attribute__((ext_vector_type(4)));

__device__ __forceinline__ float sigmoidf_acc(float x) {
    return 1.0f / (1.0f + expf(-x));
}

__device__ __forceinline__ unsigned int pack2(float a, float b) {
    __half2 h = __floats2half2_rn(a, b);
    return *reinterpret_cast<unsigned int*>(&h);
}

__device__ __forceinline__ float2 unpack2(unsigned int u) {
    __half2 h = *reinterpret_cast<__half2*>(&u);
    return __half22float2(h);
}

__device__ __forceinline__ void nt_store4(float* p, float x, float y, float z, float w) {
    f4v v = {x, y, z, w};
    __builtin_nontemporal_store(v, (f4v*)p);
}

// ---------------- Fused pre-pass: activate + fold covariance + partial mean/var ----
// 1 entry per thread. Entry j -> 16 fp16 at tabu[2*j .. 2*j+1] (uint4 pair):
//   words: (p0,p1)(p2,c00) | (c01,c02)(c11,c12) | (c22,sh0)(sh1,sh2) | (op,0)(0,0)
// p0..p2 RAW; normalization folded into gather kernel.

__global__ __launch_bounds__(256) void prepass_kernel(
    const float* __restrict__ ht,
    const float* __restrict__ farp,
    const int* __restrict__ vsp,
    double* __restrict__ part, int nblocks,
    uint4* __restrict__ tabu)
{
    int t = blockIdx.x * blockDim.x + threadIdx.x;   // grid exact: TABLE_SIZE/256

    float p[14];
    #pragma unroll
    for (int r = 0; r < 14; ++r) p[r] = ht[(size_t)r * TABLE_SIZE + t];

    float far = farp[0];
    float vs  = (float)vsp[0];
    float scale_fac = 2.0f * far / vs;

    float q0 = p[3], q1 = p[4], q2 = p[5], q3 = p[6];
    float s0 = sigmoidf_acc(p[7]) * scale_fac;
    float s1 = sigmoidf_acc(p[8]) * scale_fac;
    float s2 = sigmoidf_acc(p[9]) * scale_fac;
    float sh0 = sigmoidf_acc(p[10]);
    float sh1 = sigmoidf_acc(p[11]);
    float sh2 = sigmoidf_acc(p[12]);
    float op  = sigmoidf_acc(p[13] - 4.0f);

    float qn = 1.0f / sqrtf(q0 * q0 + q1 * q1 + q2 * q2 + q3 * q3);
    float r = q0 * qn, x = q1 * qn, y = q2 * qn, z = q3 * qn;

    float R00 = 1.0f - 2.0f * (y * y + z * z);
    float R01 = 2.0f * (x * y - r * z);
    float R02 = 2.0f * (x * z + r * y);
    float R10 = 2.0f * (x * y + r * z);
    float R11 = 1.0f - 2.0f * (x * x + z * z);
    float R12 = 2.0f * (y * z - r * x);
    float R20 = 2.0f * (x * z - r * y);
    float R21 = 2.0f * (y * z + r * x);
    float R22 = 1.0f - 2.0f * (x * x + y * y);

    float L00 = R00 * s0, L01 = R01 * s1, L02 = R02 * s2;
    float L10 = R10 * s0, L11 = R11 * s1, L12 = R12 * s2;
    float L20 = R20 * s0, L21 = R21 * s1, L22 = R22 * s2;

    float c00 = L00 * L00 + L01 * L01 + L02 * L02;
    float c01 = L00 * L10 + L01 * L11 + L02 * L12;
    float c02 = L00 * L20 + L01 * L21 + L02 * L22;
    float c11 = L10 * L10 + L11 * L11 + L12 * L12;
    float c12 = L10 * L20 + L11 * L21 + L12 * L22;
    float c22 = L20 * L20 + L21 * L21 + L22 * L22;

    tabu[2 * t + 0] = make_uint4(pack2(p[0], p[1]), pack2(p[2], c00),
                                 pack2(c01, c02),   pack2(c11, c12));
    tabu[2 * t + 1] = make_uint4(pack2(c22, sh0),   pack2(sh1, sh2),
                                 pack2(op, 0.0f),   0u);

    // partial sum / sumsq over rows 0..2
    double rsum  = (double)p[0] + (double)p[1] + (double)p[2];
    double rsum2 = (double)p[0]*p[0] + (double)p[1]*p[1] + (double)p[2]*p[2];

    for (int off = 32; off > 0; off >>= 1) {
        rsum  += __shfl_down(rsum, off, 64);
        rsum2 += __shfl_down(rsum2, off, 64);
    }
    __shared__ double ls[4], ls2[4];
    int wid = threadIdx.x >> 6;
    if ((threadIdx.x & 63) == 0) { ls[wid] = rsum; ls2[wid] = rsum2; }
    __syncthreads();
    if (threadIdx.x == 0) {
        double sa = 0.0, sb = 0.0;
        for (int w = 0; w < 4; ++w) { sa += ls[w]; sb += ls2[w]; }
        part[blockIdx.x] = sa;
        part[nblocks + blockIdx.x] = sb;
    }
}

__global__ __launch_bounds__(256) void reduce_final_kernel(
    double* __restrict__ part, int nblocks)
{
    double s = 0.0, s2 = 0.0;
    for (int i = threadIdx.x; i < nblocks; i += blockDim.x) {
        s  += part[i];
        s2 += part[nblocks + i];
    }
    for (int off = 32; off > 0; off >>= 1) {
        s  += __shfl_down(s, off, 64);
        s2 += __shfl_down(s2, off, 64);
    }
    __shared__ double ls[4], ls2[4];
    int wid = threadIdx.x >> 6;
    if ((threadIdx.x & 63) == 0) { ls[wid] = s; ls2[wid] = s2; }
    __syncthreads();
    if (threadIdx.x == 0) {
        double a = 0.0, b = 0.0;
        for (int w = 0; w < 4; ++w) { a += ls[w]; b += ls2[w]; }
        double n = 3.0 * (double)TABLE_SIZE;
        double mean = a / n;
        double var = (b - n * mean * mean) / (n - 1.0);
        part[2 * nblocks]     = mean;
        part[2 * nblocks + 1] = 1.0 / sqrt(var);
    }
}

// ---------------- Main per-point kernel (gather path) ------------

__global__ __launch_bounds__(256) void HashTableVoxelizedGaussianAdapterModule_86990267613197_kernel(
    const int* __restrict__ coords,
    const uint4* __restrict__ tabu,
    const float* __restrict__ cam,
    const float* __restrict__ farp,
    const int* __restrict__ vsp,
    const double* __restrict__ stats,
    float* __restrict__ out)
{
    int i = blockIdx.x * blockDim.x + threadIdx.x;   // exact grid: NPTS/256

    int c0 = coords[3 * i + 0];
    int c1 = coords[3 * i + 1];
    int c2 = coords[3 * i + 2];

    unsigned int h = (unsigned int)c0 * 1u
                   ^ (unsigned int)c1 * 2654435761u
                   ^ (unsigned int)c2 * 805459861u;
    int idx = (int)(h & (unsigned int)(TABLE_SIZE - 1));

    uint4 w0 = tabu[2 * idx + 0];
    uint4 w1 = tabu[2 * idx + 1];

    float2 p01   = unpack2(w0.x);   // p0 p1
    float2 p2c00 = unpack2(w0.y);   // p2 c00
    float2 c0102 = unpack2(w0.z);   // c01 c02
    float2 c1112 = unpack2(w0.w);   // c11 c12
    float2 c22s0 = unpack2(w1.x);   // c22 sh0
    float2 s1s2  = unpack2(w1.y);   // sh1 sh2
    float2 opz   = unpack2(w1.z);   // op 0

    float far = farp[0];
    float vs  = (float)vsp[0];
    float k   = 2.0f * far / vs;
    float off = -far + far / vs;

    float mean   = (float)stats[0];
    float invstd = (float)stats[1];
    float nf = invstd * (k / 6.0f);          // k == scale_fac

    float vcx = (float)c0 * k + off + cam[0];
    float vcy = (float)c1 * k + off + cam[1];
    float vcz = (float)c2 * k + off + cam[2];

    float* o = out + 16LL * i;
    nt_store4(o + 0,  (p01.x - mean) * nf + vcx,
                      (p01.y - mean) * nf + vcy,
                      (p2c00.x - mean) * nf + vcz, p2c00.y);
    nt_store4(o + 4,  c0102.x, c0102.y, c0102.x, c1112.x);   // c01 c02 c01 c11
    nt_store4(o + 8,  c1112.y, c0102.y, c1112.y, c22s0.x);   // c12 c02 c12 c22
    nt_store4(o + 12, c22s0.y, s1s2.x, s1s2.y, opz.x);       // sh0 sh1 sh2 op
}

// ---------------- Fallback path (ws too small): reduction + direct kernel ---------

__global__ __launch_bounds__(256) void reduce_partial_kernel(
    const float4* __restrict__ ht4, double* __restrict__ part, int nblocks)
{
    const int total4 = 3 * TABLE_SIZE / 4;
    double s = 0.0, s2 = 0.0;
    int stride = gridDim.x * blockDim.x;
    for (int i = blockIdx.x * blockDim.x + threadIdx.x; i < total4; i += stride) {
        float4 v = ht4[i];
        double a = (double)v.x, b = (double)v.y, c = (double)v.z, d = (double)v.w;
        s  += a + b + c + d;
        s2 += a * a + b * b + c * c + d * d;
    }
    for (int off = 32; off > 0; off >>= 1) {
        s  += __shfl_down(s, off, 64);
        s2 += __shfl_down(s2, off, 64);
    }
    __shared__ double ls[4], ls2[4];
    int wid = threadIdx.x >> 6;
    if ((threadIdx.x & 63) == 0) { ls[wid] = s; ls2[wid] = s2; }
    __syncthreads();
    if (threadIdx.x == 0) {
        double a = 0.0, b = 0.0;
        for (int w = 0; w < 4; ++w) { a += ls[w]; b += ls2[w]; }
        part[blockIdx.x] = a;
        part[nblocks + blockIdx.x] = b;
    }
}

__global__ __launch_bounds__(256) void direct_kernel(
    const int* __restrict__ coords,
    const float* __restrict__ ht,
    const float* __restrict__ cam,
    const float* __restrict__ farp,
    const int* __restrict__ vsp,
    const double* __restrict__ stats,
    float* __restrict__ out)
{
    int i = blockIdx.x * blockDim.x + threadIdx.x;
    if (i >= NPTS) return;

    int c0 = coords[3 * i + 0];
    int c1 = coords[3 * i + 1];
    int c2 = coords[3 * i + 2];

    unsigned int h = (unsigned int)c0 * 1u
                   ^ (unsigned int)c1 * 2654435761u
                   ^ (unsigned int)c2 * 805459861u;
    int idx = (int)(h & (unsigned int)(TABLE_SIZE - 1));

    float far = farp[0];
    float vs  = (float)vsp[0];
    float scale_fac = 2.0f * far / vs;
    float mean   = (float)stats[0];
    float invstd = (float)stats[1];

    const float* p = ht + idx;
    float nf = invstd * (scale_fac / 6.0f);
    float f0 = (p[0 * TABLE_SIZE] - mean) * nf;
    float f1 = (p[1 * TABLE_SIZE] - mean) * nf;
    float f2 = (p[2 * TABLE_SIZE] - mean) * nf;
    float q0 = p[3 * TABLE_SIZE];
    float q1 = p[4 * TABLE_SIZE];
    float q2 = p[5 * TABLE_SIZE];
    float q3 = p[6 * TABLE_SIZE];
    float s0 = sigmoidf_acc(p[7 * TABLE_SIZE]) * scale_fac;
    float s1 = sigmoidf_acc(p[8 * TABLE_SIZE]) * scale_fac;
    float s2 = sigmoidf_acc(p[9 * TABLE_SIZE]) * scale_fac;
    float sh0 = sigmoidf_acc(p[10 * TABLE_SIZE]);
    float sh1 = sigmoidf_acc(p[11 * TABLE_SIZE]);
    float sh2 = sigmoidf_acc(p[12 * TABLE_SIZE]);
    float op  = sigmoidf_acc(p[13 * TABLE_SIZE] - 4.0f);

    float k = 2.0f * far / vs;
    float off = -far + far / vs;
    float vcx = (float)c0 * k + off + cam[0];
    float vcy = (float)c1 * k + off + cam[1];
    float vcz = (float)c2 * k + off + cam[2];

    float qn = 1.0f / sqrtf(q0 * q0 + q1 * q1 + q2 * q2 + q3 * q3);
    float r = q0 * qn, x = q1 * qn, y = q2 * qn, z = q3 * qn;

    float R00 = 1.0f - 2.0f * (y * y + z * z);
    float R01 = 2.0f * (x * y - r * z);
    float R02 = 2.0f * (x * z + r * y);
    float R10 = 2.0f * (x * y + r * z);
    float R11 = 1.0f - 2.0f * (x * x + z * z);
    float R12 = 2.0f * (y * z - r * x);
    float R20 = 2.0f * (x * z - r * y);
    float R21 = 2.0f * (y * z + r * x);
    float R22 = 1.0f - 2.0f * (x * x + y * y);

    float L00 = R00 * s0, L01 = R01 * s1, L02 = R02 * s2;
    float L10 = R10 * s0, L11 = R11 * s1, L12 = R12 * s2;
    float L20 = R20 * s0, L21 = R21 * s1, L22 = R22 * s2;

    float c00 = L00 * L00 + L01 * L01 + L02 * L02;
    float c01 = L00 * L10 + L01 * L11 + L02 * L12;
    float c02 = L00 * L20 + L01 * L21 + L02 * L22;
    float c11 = L10 * L10 + L11 * L11 + L12 * L12;
    float c12 = L10 * L20 + L11 * L21 + L12 * L22;
    float c22 = L20 * L20 + L21 * L21 + L22 * L22;

    float4* o = (float4*)(out + 16LL * i);
    o[0] = make_float4(f0 + vcx, f1 + vcy, f2 + vcz, c00);
    o[1] = make_float4(c01, c02, c01, c11);
    o[2] = make_float4(c12, c02, c12, c22);
    o[3] = make_float4(sh0, sh1, sh2, op);
}

// ---------------- Launch ----------------

extern "C" void kernel_launch(void* const* d_in, const int* in_sizes, int n_in,
                              void* d_out, int out_size, void* d_ws, size_t ws_size,
                              hipStream_t stream) {
    const int*   coords = (const int*)d_in[0];
    const float* ht     = (const float*)d_in[1];
    const float* cam    = (const float*)d_in[2];
    const float* farp   = (const float*)d_in[3];
    const int*   vsp    = (const int*)d_in[4];
    float* out = (float*)d_out;

    const int nbA = TABLE_SIZE / 256;                         // 16384 pre-pass blocks
    const size_t red_bytes = (((2 * (size_t)nbA + 2) * sizeof(double)) + 4095) & ~(size_t)4095;
    const size_t tab_bytes = (size_t)TABLE_SIZE * 32;         // fp16 tab: 134.2 MB

    double* ws = (double*)d_ws;

    if (ws_size >= red_bytes + tab_bytes) {
        uint4* tabu = (uint4*)((char*)d_ws + red_bytes);
        prepass_kernel<<<nbA, 256, 0, stream>>>(ht, farp, vsp, ws, nbA, tabu);
        reduce_final_kernel<<<1, 256, 0, stream>>>(ws, nbA);
        const double* stats = ws + 2 * nbA;
        HashTableVoxelizedGaussianAdapterModule_86990267613197_kernel<<<NPTS / 256, 256, 0, stream>>>(
            coords, tabu, cam, farp, vsp, stats, out);
    } else {
        const int nb = 1024;
        reduce_partial_kernel<<<nb, 256, 0, stream>>>((const float4*)ht, ws, nb);
        reduce_final_kernel<<<1, 256, 0, stream>>>(ws, nb);
        const double* stats = ws + 2 * nb;
        direct_kernel<<<(NPTS + 255) / 256, 256, 0, stream>>>(
            coords, ht, cam, farp, vsp, stats, out);
    }
}